// Round 5
// baseline (581.708 us; speedup 1.0000x reference)
//
#include <hip/hip_runtime.h>
#include <cstddef>

// StreamingISTFT: denormalize -> irfft(2048) over freq axis -> window -> overlap-add.
// B=8, F=1024(+Nyquist pad), T=2048, HOP=512, FRAME_LEN=2048.
// irfft(2048) = complex IFFT(1024) (real-packing trick); IFFT(1024) as four-step
// 32x32 so every global access is contiguous in t. FFT32 fully in registers.
//
// R5: (a) __powf -> __builtin_amdgcn_logf/exp2f (native v_log_f32/v_exp_f32;
// R4's __exp2f collided with glibc math.h). R1-vs-R3 VALU-cycle ratio 1.99
// fingerprinted __ocml_pow_f32 (~80 inst/call, 64 calls/thread) as the hog.
// (b) __launch_bounds__(256,4) caps VGPR at 128 -> 4 waves/SIMD (R1/R3 showed
// an occupancy cliff to ~1 wave/SIMD at VGPR>128).

#define TDIM 2048
#define FDIM 1024

static constexpr int kBREV[32] = {0,16,8,24,4,20,12,28,2,18,10,26,6,22,14,30,
                                  1,17,9,25,5,21,13,29,3,19,11,27,7,23,15,31};
// e^{+2*pi*i*r/32}, r=0..15 (inverse-transform sign)
static constexpr float kTR[16] = {
  1.0f, 0.98078528040323044f, 0.92387953251128674f, 0.83146961230254524f,
  0.70710678118654757f, 0.55557023301960218f, 0.38268343236508978f, 0.19509032201612825f,
  0.0f, -0.19509032201612825f, -0.38268343236508978f, -0.55557023301960218f,
  -0.70710678118654757f, -0.83146961230254524f, -0.92387953251128674f, -0.98078528040323044f};
static constexpr float kTI[16] = {
  0.0f, 0.19509032201612825f, 0.38268343236508978f, 0.55557023301960218f,
  0.70710678118654757f, 0.83146961230254524f, 0.92387953251128674f, 0.98078528040323044f,
  1.0f, 0.98078528040323044f, 0.92387953251128674f, 0.83146961230254524f,
  0.70710678118654757f, 0.55557023301960218f, 0.38268343236508978f, 0.19509032201612825f};

// One radix-2 stage, half-span H. All indices literal constants after
// specialization -> SROA keeps ar/ai in VGPRs.
template <int H>
__device__ __forceinline__ void fft32_stage(float ar[32], float ai[32]) {
  constexpr int TSTEP = 16 / H;
  #pragma unroll
  for (int g = 0; g < 32; g += 2 * H) {
    #pragma unroll
    for (int j = 0; j < H; ++j) {
      const float twr = kTR[j * TSTEP];
      const float twi = kTI[j * TSTEP];
      const int i0 = g + j, i1 = i0 + H;
      const float tr = twr * ar[i1] - twi * ai[i1];
      const float ti = twr * ai[i1] + twi * ar[i1];
      ar[i1] = ar[i0] - tr; ai[i1] = ai[i0] - ti;
      ar[i0] += tr;         ai[i0] += ti;
    }
  }
}

// In-register radix-2 DIT FFT32 (inverse sign). Input already bit-reversed;
// output natural: out[m] = sum_k in_nat[k] e^{+2 pi i k m/32}.
__device__ __forceinline__ void ifft32_core(float ar[32], float ai[32]) {
  fft32_stage<1>(ar, ai);
  fft32_stage<2>(ar, ai);
  fft32_stage<4>(ar, ai);
  fft32_stage<8>(ar, ai);
  fft32_stage<16>(ar, ai);
}

// |v|^(2*PE) * KS via native v_log_f32 + v_exp_f32. v=0 -> log2=-inf -> exp2=0: ok.
__device__ __forceinline__ float pow_gain(float v, float PE, float KS) {
  return KS * __builtin_amdgcn_exp2f(PE * __builtin_amdgcn_logf(v));
}

// Pass 1: denormalize + Hermitian W-packing + FFT32 over k2 + inter-stage twiddle.
// One class k1 per block; mirror values loaded straight from global (uniform path).
// blockIdx: x = t-tile (8x256), y = class k1 (32), z = batch.
__global__ __launch_bounds__(256, 4) void istft_pass1(const float* __restrict__ in,
                                                      float2* __restrict__ A) {
  const int t  = blockIdx.x * 256 + threadIdx.x;
  const int k1 = blockIdx.y;
  const int b  = blockIdx.z;
  const float* re_p = in + ((size_t)b * 2 + 0) * ((size_t)FDIM * TDIM);
  const float* im_p = in + ((size_t)b * 2 + 1) * ((size_t)FDIM * TDIM);
  float2* Ab = A + (size_t)b * FDIM * TDIM;

  // fold: beta^(-1/alpha) / 2048  (irfft 1/N folded in)
  const float KS = (float)(exp((-1.0 / 0.65) * log(0.06)) / 2048.0);
  const float PE = 7.0f / 26.0f;  // ((1/alpha)-1)/2

  float ar[32], ai[32];
  #pragma unroll
  for (int k2 = 0; k2 < 32; ++k2) {
    const int k  = k1 + 32 * k2;
    const int km = (1024 - k) & 1023;  // Hermitian mirror (k=0 -> 0, fixed below)
    const float x1 = re_p[(size_t)k  * TDIM + t];
    const float y1 = im_p[(size_t)k  * TDIM + t];
    const float x2 = re_p[(size_t)km * TDIM + t];
    const float y2 = im_p[(size_t)km * TDIM + t];
    const float g1 = pow_gain(x1 * x1 + y1 * y1, PE, KS);
    const float g2 = pow_gain(x2 * x2 + y2 * y2, PE, KS);
    const float s1r = x1 * g1, s1i = y1 * g1;
    const float s2r = x2 * g2, s2i = y2 * g2;
    // W[k] = (S1 + conj(S2)) + i*T*(S1 - conj(S2)),  T = e^{i pi k/1024}
    const float ang = 3.0679615757712824e-3f * (float)k;
    const float sn = __sinf(ang), cs = __cosf(ang);
    const float Pre = s1r + s2r, Pim = s1i - s2i;
    const float Qre = s1r - s2r, Qim = s1i + s2i;
    const float u = cs * Qim + sn * Qre;
    const float v = cs * Qre - sn * Qim;
    float wr = Pre - u, wi = Pim + v;
    if (k1 == 0 && k2 == 0) { wr = s1r; wi = s1r; }  // DC: Im dropped, Nyquist=0
    ar[kBREV[k2]] = wr; ai[kBREV[k2]] = wi;          // constexpr index (unrolled)
  }
  ifft32_core(ar, ai);
  // inter-stage twiddle e^{2 pi i k1 m2/1024}, store A[k1*32+m2][t]
  #pragma unroll
  for (int m2 = 0; m2 < 32; ++m2) {
    const float ang = 6.1359231515425649e-3f * (float)(k1 * m2);
    const float sn = __sinf(ang), cs = __cosf(ang);
    const float vr = cs * ar[m2] - sn * ai[m2];
    const float vi = cs * ai[m2] + sn * ar[m2];
    Ab[(size_t)(k1 * 32 + m2) * TDIM + t] = make_float2(vr, vi);
  }
}

// Pass 2: FFT32 over k1 (rows k1*32+m2) -> z[m2+32*m1]; x[2m]=Re z, x[2m+1]=Im z;
// multiply by inv_window; store frames[l][t].
__global__ __launch_bounds__(256, 4) void istft_pass2(const float2* __restrict__ A,
                                                      const float* __restrict__ invw,
                                                      float* __restrict__ frames) {
  const int t  = blockIdx.x * 256 + threadIdx.x;
  const int m2 = blockIdx.y;
  const int b  = blockIdx.z;
  const float2* Ab = A + (size_t)b * FDIM * TDIM;
  float* fb = frames + (size_t)b * TDIM * TDIM;
  float ar[32], ai[32];
  #pragma unroll
  for (int i = 0; i < 32; ++i) {  // load directly in bit-reversed order
    const float2 v = Ab[(size_t)(kBREV[i] * 32 + m2) * TDIM + t];
    ar[i] = v.x; ai[i] = v.y;
  }
  ifft32_core(ar, ai);
  #pragma unroll
  for (int m1 = 0; m1 < 32; ++m1) {
    const int m = m2 + 32 * m1;
    fb[(size_t)(2 * m)     * TDIM + t] = ar[m1] * invw[2 * m];
    fb[(size_t)(2 * m + 1) * TDIM + t] = ai[m1] * invw[2 * m + 1];
  }
}

// Pass 3: overlap-add gather + transpose. out[b][512h+j] = sum_c frames[b][j+512c][h-c].
__global__ __launch_bounds__(256) void istft_pass3(const float* __restrict__ frames,
                                                   float* __restrict__ out) {
  __shared__ float tile[64][65];  // [j'][h'], +1 pad: transposed read conflict-free
  const int j0 = blockIdx.x * 64;
  const int h0 = blockIdx.y * 64;
  const int b  = blockIdx.z;
  const int lane = threadIdx.x & 63;
  const int grp  = threadIdx.x >> 6;
  const float* fb = frames + (size_t)b * TDIM * TDIM;
  #pragma unroll
  for (int rr = grp; rr < 64; rr += 4) {
    const int j = j0 + rr;
    float acc = 0.0f;
    #pragma unroll
    for (int c = 0; c < 4; ++c) {
      const int hcol = h0 + lane - c;
      if (hcol >= 0) acc += fb[(size_t)(j + 512 * c) * TDIM + hcol];
    }
    tile[rr][lane] = acc;
  }
  __syncthreads();
  float* ob = out + (size_t)b * (size_t)(512 * 2048);
  #pragma unroll
  for (int hh = grp; hh < 64; hh += 4) {
    ob[(size_t)(h0 + hh) * 512 + j0 + lane] = tile[lane][hh];
  }
}

extern "C" void kernel_launch(void* const* d_in, const int* in_sizes, int n_in,
                              void* d_out, int out_size, void* d_ws, size_t ws_size,
                              hipStream_t stream) {
  (void)in_sizes; (void)n_in; (void)out_size;
  const float* in   = (const float*)d_in[0];
  const float* invw = (const float*)d_in[1];
  float* out = (float*)d_out;
  const size_t perA = (size_t)FDIM * TDIM * sizeof(float2);  // 16 MiB / batch
  const size_t perF = (size_t)TDIM * TDIM * sizeof(float);   // 16 MiB / batch
  int nb = (int)(ws_size / (perA + perF));
  if (nb < 1) nb = 1;
  if (nb > 8) nb = 8;
  for (int b0 = 0; b0 < 8; b0 += nb) {
    const int cnt = (8 - b0 < nb) ? (8 - b0) : nb;
    float2* A     = (float2*)d_ws;
    float* frames = (float*)((char*)d_ws + (size_t)cnt * perA);
    istft_pass1<<<dim3(8, 32, cnt), 256, 0, stream>>>(
        in + (size_t)b0 * 2 * FDIM * TDIM, A);
    istft_pass2<<<dim3(8, 32, cnt), 256, 0, stream>>>(A, invw, frames);
    istft_pass3<<<dim3(8, 32, cnt), 256, 0, stream>>>(
        frames, out + (size_t)b0 * (size_t)(512 * 2048));
  }
}

// Round 6
// 318.160 us; speedup vs baseline: 1.8284x; 1.8284x over previous
//
#include <hip/hip_runtime.h>
#include <cstddef>

// StreamingISTFT: denormalize -> irfft(2048) over freq axis -> window -> overlap-add.
// B=8, F=1024(+Nyquist pad), T=2048, HOP=512, FRAME_LEN=2048.
// irfft(2048) = complex IFFT(1024) (real-packing trick); IFFT(1024) as four-step
// 32x32 so every global access is contiguous in t. FFT32 fully in registers.
//
// R6: native transcendentals (R5 proved: VALU-cycles 168->35 us-equiv) WITHOUT
// any launch_bounds min-wave cap (R2/R5 proved: forcing below the natural ~164
// VGPR makes the allocator dive to 64 and spill ~850 MB of scratch traffic).
// Natural allocation (R3: VGPR=164) is spill-free: WRITE_SIZE=131072 KB exact.

#define TDIM 2048
#define FDIM 1024

static constexpr int kBREV[32] = {0,16,8,24,4,20,12,28,2,18,10,26,6,22,14,30,
                                  1,17,9,25,5,21,13,29,3,19,11,27,7,23,15,31};
// e^{+2*pi*i*r/32}, r=0..15 (inverse-transform sign)
static constexpr float kTR[16] = {
  1.0f, 0.98078528040323044f, 0.92387953251128674f, 0.83146961230254524f,
  0.70710678118654757f, 0.55557023301960218f, 0.38268343236508978f, 0.19509032201612825f,
  0.0f, -0.19509032201612825f, -0.38268343236508978f, -0.55557023301960218f,
  -0.70710678118654757f, -0.83146961230254524f, -0.92387953251128674f, -0.98078528040323044f};
static constexpr float kTI[16] = {
  0.0f, 0.19509032201612825f, 0.38268343236508978f, 0.55557023301960218f,
  0.70710678118654757f, 0.83146961230254524f, 0.92387953251128674f, 0.98078528040323044f,
  1.0f, 0.98078528040323044f, 0.92387953251128674f, 0.83146961230254524f,
  0.70710678118654757f, 0.55557023301960218f, 0.38268343236508978f, 0.19509032201612825f};

// One radix-2 stage, half-span H. All indices literal constants after
// specialization -> SROA keeps ar/ai in VGPRs.
template <int H>
__device__ __forceinline__ void fft32_stage(float ar[32], float ai[32]) {
  constexpr int TSTEP = 16 / H;
  #pragma unroll
  for (int g = 0; g < 32; g += 2 * H) {
    #pragma unroll
    for (int j = 0; j < H; ++j) {
      const float twr = kTR[j * TSTEP];
      const float twi = kTI[j * TSTEP];
      const int i0 = g + j, i1 = i0 + H;
      const float tr = twr * ar[i1] - twi * ai[i1];
      const float ti = twr * ai[i1] + twi * ar[i1];
      ar[i1] = ar[i0] - tr; ai[i1] = ai[i0] - ti;
      ar[i0] += tr;         ai[i0] += ti;
    }
  }
}

// In-register radix-2 DIT FFT32 (inverse sign). Input already bit-reversed;
// output natural: out[m] = sum_k in_nat[k] e^{+2 pi i k m/32}.
__device__ __forceinline__ void ifft32_core(float ar[32], float ai[32]) {
  fft32_stage<1>(ar, ai);
  fft32_stage<2>(ar, ai);
  fft32_stage<4>(ar, ai);
  fft32_stage<8>(ar, ai);
  fft32_stage<16>(ar, ai);
}

// |v|^(2*PE) * KS via native v_log_f32 + v_exp_f32. v=0 -> log2=-inf -> exp2=0: ok.
__device__ __forceinline__ float pow_gain(float v, float PE, float KS) {
  return KS * __builtin_amdgcn_exp2f(PE * __builtin_amdgcn_logf(v));
}

// Pass 1: denormalize + Hermitian W-packing + FFT32 over k2 + inter-stage twiddle.
// One class k1 per block; mirror values loaded straight from global (uniform path).
// blockIdx: x = t-tile (8x256), y = class k1 (32), z = batch.
__global__ __launch_bounds__(256) void istft_pass1(const float* __restrict__ in,
                                                   float2* __restrict__ A) {
  const int t  = blockIdx.x * 256 + threadIdx.x;
  const int k1 = blockIdx.y;
  const int b  = blockIdx.z;
  const float* re_p = in + ((size_t)b * 2 + 0) * ((size_t)FDIM * TDIM);
  const float* im_p = in + ((size_t)b * 2 + 1) * ((size_t)FDIM * TDIM);
  float2* Ab = A + (size_t)b * FDIM * TDIM;

  // fold: beta^(-1/alpha) / 2048  (irfft 1/N folded in)
  const float KS = (float)(exp((-1.0 / 0.65) * log(0.06)) / 2048.0);
  const float PE = 7.0f / 26.0f;  // ((1/alpha)-1)/2

  float ar[32], ai[32];
  #pragma unroll
  for (int k2 = 0; k2 < 32; ++k2) {
    const int k  = k1 + 32 * k2;
    const int km = (1024 - k) & 1023;  // Hermitian mirror (k=0 -> 0, fixed below)
    const float x1 = re_p[(size_t)k  * TDIM + t];
    const float y1 = im_p[(size_t)k  * TDIM + t];
    const float x2 = re_p[(size_t)km * TDIM + t];
    const float y2 = im_p[(size_t)km * TDIM + t];
    const float g1 = pow_gain(x1 * x1 + y1 * y1, PE, KS);
    const float g2 = pow_gain(x2 * x2 + y2 * y2, PE, KS);
    const float s1r = x1 * g1, s1i = y1 * g1;
    const float s2r = x2 * g2, s2i = y2 * g2;
    // W[k] = (S1 + conj(S2)) + i*T*(S1 - conj(S2)),  T = e^{i pi k/1024}
    const float ang = 3.0679615757712824e-3f * (float)k;
    const float sn = __sinf(ang), cs = __cosf(ang);
    const float Pre = s1r + s2r, Pim = s1i - s2i;
    const float Qre = s1r - s2r, Qim = s1i + s2i;
    const float u = cs * Qim + sn * Qre;
    const float v = cs * Qre - sn * Qim;
    float wr = Pre - u, wi = Pim + v;
    if (k1 == 0 && k2 == 0) { wr = s1r; wi = s1r; }  // DC: Im dropped, Nyquist=0
    ar[kBREV[k2]] = wr; ai[kBREV[k2]] = wi;          // constexpr index (unrolled)
  }
  ifft32_core(ar, ai);
  // inter-stage twiddle e^{2 pi i k1 m2/1024}, store A[k1*32+m2][t]
  #pragma unroll
  for (int m2 = 0; m2 < 32; ++m2) {
    const float ang = 6.1359231515425649e-3f * (float)(k1 * m2);
    const float sn = __sinf(ang), cs = __cosf(ang);
    const float vr = cs * ar[m2] - sn * ai[m2];
    const float vi = cs * ai[m2] + sn * ar[m2];
    Ab[(size_t)(k1 * 32 + m2) * TDIM + t] = make_float2(vr, vi);
  }
}

// Pass 2: FFT32 over k1 (rows k1*32+m2) -> z[m2+32*m1]; x[2m]=Re z, x[2m+1]=Im z;
// multiply by inv_window; store frames[l][t].
__global__ __launch_bounds__(256) void istft_pass2(const float2* __restrict__ A,
                                                   const float* __restrict__ invw,
                                                   float* __restrict__ frames) {
  const int t  = blockIdx.x * 256 + threadIdx.x;
  const int m2 = blockIdx.y;
  const int b  = blockIdx.z;
  const float2* Ab = A + (size_t)b * FDIM * TDIM;
  float* fb = frames + (size_t)b * TDIM * TDIM;
  float ar[32], ai[32];
  #pragma unroll
  for (int i = 0; i < 32; ++i) {  // load directly in bit-reversed order
    const float2 v = Ab[(size_t)(kBREV[i] * 32 + m2) * TDIM + t];
    ar[i] = v.x; ai[i] = v.y;
  }
  ifft32_core(ar, ai);
  #pragma unroll
  for (int m1 = 0; m1 < 32; ++m1) {
    const int m = m2 + 32 * m1;
    fb[(size_t)(2 * m)     * TDIM + t] = ar[m1] * invw[2 * m];
    fb[(size_t)(2 * m + 1) * TDIM + t] = ai[m1] * invw[2 * m + 1];
  }
}

// Pass 3: overlap-add gather + transpose. out[b][512h+j] = sum_c frames[b][j+512c][h-c].
__global__ __launch_bounds__(256) void istft_pass3(const float* __restrict__ frames,
                                                   float* __restrict__ out) {
  __shared__ float tile[64][65];  // [j'][h'], +1 pad: transposed read conflict-free
  const int j0 = blockIdx.x * 64;
  const int h0 = blockIdx.y * 64;
  const int b  = blockIdx.z;
  const int lane = threadIdx.x & 63;
  const int grp  = threadIdx.x >> 6;
  const float* fb = frames + (size_t)b * TDIM * TDIM;
  #pragma unroll
  for (int rr = grp; rr < 64; rr += 4) {
    const int j = j0 + rr;
    float acc = 0.0f;
    #pragma unroll
    for (int c = 0; c < 4; ++c) {
      const int hcol = h0 + lane - c;
      if (hcol >= 0) acc += fb[(size_t)(j + 512 * c) * TDIM + hcol];
    }
    tile[rr][lane] = acc;
  }
  __syncthreads();
  float* ob = out + (size_t)b * (size_t)(512 * 2048);
  #pragma unroll
  for (int hh = grp; hh < 64; hh += 4) {
    ob[(size_t)(h0 + hh) * 512 + j0 + lane] = tile[lane][hh];
  }
}

extern "C" void kernel_launch(void* const* d_in, const int* in_sizes, int n_in,
                              void* d_out, int out_size, void* d_ws, size_t ws_size,
                              hipStream_t stream) {
  (void)in_sizes; (void)n_in; (void)out_size;
  const float* in   = (const float*)d_in[0];
  const float* invw = (const float*)d_in[1];
  float* out = (float*)d_out;
  const size_t perA = (size_t)FDIM * TDIM * sizeof(float2);  // 16 MiB / batch
  const size_t perF = (size_t)TDIM * TDIM * sizeof(float);   // 16 MiB / batch
  int nb = (int)(ws_size / (perA + perF));
  if (nb < 1) nb = 1;
  if (nb > 8) nb = 8;
  for (int b0 = 0; b0 < 8; b0 += nb) {
    const int cnt = (8 - b0 < nb) ? (8 - b0) : nb;
    float2* A     = (float2*)d_ws;
    float* frames = (float*)((char*)d_ws + (size_t)cnt * perA);
    istft_pass1<<<dim3(8, 32, cnt), 256, 0, stream>>>(
        in + (size_t)b0 * 2 * FDIM * TDIM, A);
    istft_pass2<<<dim3(8, 32, cnt), 256, 0, stream>>>(A, invw, frames);
    istft_pass3<<<dim3(8, 32, cnt), 256, 0, stream>>>(
        frames, out + (size_t)b0 * (size_t)(512 * 2048));
  }
}

// Round 7
// 309.989 us; speedup vs baseline: 1.8765x; 1.0264x over previous
//
#include <hip/hip_runtime.h>
#include <cstddef>

// StreamingISTFT fully fused: denorm+pack -> FFT32(k2) -> LDS -> FFT32(k1)
// -> window -> LDS frame tile -> overlap-add -> coalesced stores.
// B=8, F=1024(+Nyquist), T=2048, HOP=512, L=2048.
// irfft(2048) = complex IFFT(1024) (real-packing); IFFT(1024) = 32x32 four-step.
//
// R7: single-kernel fusion. OLA identity: contribution of frames[l][t] goes to
// out[512*t + l]; all 4 contributors to an output share l mod 64 -> a block
// owning all 1024 freqs for an 8-wide t-tile completes the OLA locally.
// Tile-boundary output columns (rel 0..2, 8..10) get partial sums from two
// adjacent blocks -> coalesced atomicAdd onto memset-zeroed output.
// Eliminates both intermediates (A, frames: 536 MB of round-trip traffic) and
// two kernel-latency exposures. LDS 67.6 KB -> 2 blocks/CU; X-tile strides
// (k1:264, r:8, t:1) give exactly 2-way (free) banks on both stage-1 writes
// and stage-2 reads; frame tile stride 2053 keeps OLA reads conflict-free.

#define TDIM 2048
#define FDIM 1024
#define TT 8                    // t-columns per block
#define NTOT (512 * 2048)       // output samples per batch

static constexpr int kBREV[32] = {0,16,8,24,4,20,12,28,2,18,10,26,6,22,14,30,
                                  1,17,9,25,5,21,13,29,3,19,11,27,7,23,15,31};
// e^{+2*pi*i*r/32}, r=0..15 (inverse-transform sign)
static constexpr float kTR[16] = {
  1.0f, 0.98078528040323044f, 0.92387953251128674f, 0.83146961230254524f,
  0.70710678118654757f, 0.55557023301960218f, 0.38268343236508978f, 0.19509032201612825f,
  0.0f, -0.19509032201612825f, -0.38268343236508978f, -0.55557023301960218f,
  -0.70710678118654757f, -0.83146961230254524f, -0.92387953251128674f, -0.98078528040323044f};
static constexpr float kTI[16] = {
  0.0f, 0.19509032201612825f, 0.38268343236508978f, 0.55557023301960218f,
  0.70710678118654757f, 0.83146961230254524f, 0.92387953251128674f, 0.98078528040323044f,
  1.0f, 0.98078528040323044f, 0.92387953251128674f, 0.83146961230254524f,
  0.70710678118654757f, 0.55557023301960218f, 0.38268343236508978f, 0.19509032201612825f};

// One radix-2 stage, half-span H; literal indices after specialization -> SROA.
template <int H>
__device__ __forceinline__ void fft32_stage(float ar[32], float ai[32]) {
  constexpr int TSTEP = 16 / H;
  #pragma unroll
  for (int g = 0; g < 32; g += 2 * H) {
    #pragma unroll
    for (int j = 0; j < H; ++j) {
      const float twr = kTR[j * TSTEP];
      const float twi = kTI[j * TSTEP];
      const int i0 = g + j, i1 = i0 + H;
      const float tr = twr * ar[i1] - twi * ai[i1];
      const float ti = twr * ai[i1] + twi * ar[i1];
      ar[i1] = ar[i0] - tr; ai[i1] = ai[i0] - ti;
      ar[i0] += tr;         ai[i0] += ti;
    }
  }
}

// In-register radix-2 DIT FFT32 (inverse sign). Input bit-reversed; out natural.
__device__ __forceinline__ void ifft32_core(float ar[32], float ai[32]) {
  fft32_stage<1>(ar, ai);
  fft32_stage<2>(ar, ai);
  fft32_stage<4>(ar, ai);
  fft32_stage<8>(ar, ai);
  fft32_stage<16>(ar, ai);
}

// |v|^(2*PE) * KS via native v_log_f32 + v_exp_f32. v=0 -> 0: ok.
__device__ __forceinline__ float pow_gain(float v, float PE, float KS) {
  return KS * __builtin_amdgcn_exp2f(PE * __builtin_amdgcn_logf(v));
}

// X-tile layout: X(t, k1, r) = k1*264 + r*8 + t  (264 = 32*8 + 8 pad).
// Stage-1 write lanes (t,k1): bank = (8k1 + t + 8r) -> 2-way. Stage-2 read
// lanes (t,r): bank = (8r + t + 8k1) -> 2-way. Max index 8439 < 8448.
#define XIDX(t, k1, r) ((k1) * 264 + (r) * 8 + (t))
#define FSTR 2053               // frame tile row stride (odd -> spread banks)

__global__ __launch_bounds__(256) void istft_fused(const float* __restrict__ in,
                                                   const float* __restrict__ invw,
                                                   float* __restrict__ out) {
  __shared__ float buf[16896];          // 67.6 KB; X uses [0,16896), F reuses [0,16419)
  float* Xr = buf;
  float* Xi = buf + 8448;

  const int tid = threadIdx.x;
  const int tl  = tid & 7;              // t within tile
  const int q   = tid >> 3;             // k1 (stage 1) / r (stage 2)
  const int t0  = blockIdx.x * TT;
  const int t   = t0 + tl;
  const int b   = blockIdx.y;

  const float* re_p = in + ((size_t)b * 2 + 0) * ((size_t)FDIM * TDIM);
  const float* im_p = in + ((size_t)b * 2 + 1) * ((size_t)FDIM * TDIM);

  const float KS = (float)(exp((-1.0 / 0.65) * log(0.06)) / 2048.0);
  const float PE = 7.0f / 26.0f;

  // ---- Stage 1: denorm + Hermitian pack + FFT32 over k2 + twiddle -> X ----
  {
    float ar[32], ai[32];
    #pragma unroll
    for (int k2 = 0; k2 < 32; ++k2) {
      const int k  = q + 32 * k2;
      const int km = (1024 - k) & 1023;
      const float x1 = re_p[(size_t)k  * TDIM + t];
      const float y1 = im_p[(size_t)k  * TDIM + t];
      const float x2 = re_p[(size_t)km * TDIM + t];
      const float y2 = im_p[(size_t)km * TDIM + t];
      const float g1 = pow_gain(x1 * x1 + y1 * y1, PE, KS);
      const float g2 = pow_gain(x2 * x2 + y2 * y2, PE, KS);
      const float s1r = x1 * g1, s1i = y1 * g1;
      const float s2r = x2 * g2, s2i = y2 * g2;
      // W[k] = (S1 + conj(S2)) + i*T*(S1 - conj(S2)),  T = e^{i pi k/1024}
      const float ang = 3.0679615757712824e-3f * (float)k;
      const float sn = __sinf(ang), cs = __cosf(ang);
      const float Pre = s1r + s2r, Pim = s1i - s2i;
      const float Qre = s1r - s2r, Qim = s1i + s2i;
      const float u = cs * Qim + sn * Qre;
      const float v = cs * Qre - sn * Qim;
      float wr = Pre - u, wi = Pim + v;
      if (q == 0 && k2 == 0) { wr = s1r; wi = s1r; }  // DC: Im dropped, Nyquist=0
      ar[kBREV[k2]] = wr; ai[kBREV[k2]] = wi;
    }
    ifft32_core(ar, ai);
    #pragma unroll
    for (int r = 0; r < 32; ++r) {      // inter-stage twiddle e^{2 pi i k1 r/1024}
      const float ang = 6.1359231515425649e-3f * (float)(q * r);
      const float sn = __sinf(ang), cs = __cosf(ang);
      Xr[XIDX(tl, q, r)] = cs * ar[r] - sn * ai[r];
      Xi[XIDX(tl, q, r)] = cs * ai[r] + sn * ar[r];
    }
  }
  __syncthreads();

  // ---- Stage 2: FFT32 over k1 -> z; window; frame tile F[t][l] ----
  {
    float zr[32], zi[32];
    #pragma unroll
    for (int i = 0; i < 32; ++i) {      // bit-reversed k1 load order
      zr[i] = Xr[XIDX(tl, kBREV[i], q)];
      zi[i] = Xi[XIDX(tl, kBREV[i], q)];
    }
    __syncthreads();                    // all X reads done before F overwrites buf
    ifft32_core(zr, zi);
    #pragma unroll
    for (int s = 0; s < 32; ++s) {
      const int m  = q + 32 * s;
      const int l0 = 2 * m;
      buf[tl * FSTR + l0]     = zr[s] * invw[l0];
      buf[tl * FSTR + l0 + 1] = zi[s] * invw[l0 + 1];
    }
  }
  __syncthreads();

  // ---- OLA: out[512*t' + j] = sum_c F[t'-c-t0][j + 512c] ----
  float* ob = out + (size_t)b * NTOT;
  for (int rel = 0; rel < 11; ++rel) {
    const int tp = t0 + rel;
    if (tp > 2047) break;
    #pragma unroll
    for (int half = 0; half < 2; ++half) {
      const int j = tid + 256 * half;   // lanes j-consecutive -> coalesced
      float v = 0.0f;
      #pragma unroll
      for (int c = 0; c < 4; ++c) {
        const int tt = rel - c;
        if (tt >= 0 && tt < TT) v += buf[tt * FSTR + j + 512 * c];
      }
      const int n = tp * 512 + j;
      if (rel >= 3 && rel <= 7) ob[n] = v;          // all 4 contributors in-block
      else atomicAdd(&ob[n], v);                     // tile boundary: 2 writers
    }
  }
}

extern "C" void kernel_launch(void* const* d_in, const int* in_sizes, int n_in,
                              void* d_out, int out_size, void* d_ws, size_t ws_size,
                              hipStream_t stream) {
  (void)in_sizes; (void)n_in; (void)d_ws; (void)ws_size;
  const float* in   = (const float*)d_in[0];
  const float* invw = (const float*)d_in[1];
  float* out = (float*)d_out;
  hipMemsetAsync(out, 0, (size_t)out_size * sizeof(float), stream);
  istft_fused<<<dim3(TDIM / TT, 8), 256, 0, stream>>>(in, invw, out);
}